// Round 13
// baseline (181.314 us; speedup 1.0000x reference)
//
#include <hip/hip_runtime.h>

// Capsule dynamic routing — R19: R18 routing (plateau) + float4-coalesced squash.
// u_i:(B,N,DI) f32, w:(1,N,NO,DI,DE) f32, bias:(N,NO,1) f32, r=3.
// Identity: logits_r = u_ji . vsum (u_ji includes bias so bias folds in).
// Evidence chain (R1-R12):
//   - Routing ~39us/launch is INVARIANT under weight-delivery mechanism
//     (scalar K$ R2/R12, LDS broadcast R3/R18, vector R5; register variants
//     spill R4/R8/R9; coop fusion 5x worse R10; materialization BW-bound
//     R11). Parked as plateau pending disasm.
//   - Budget: 181 = 3.5 transpose + 3x39 routing + 3x~14.5 SQUASH + gaps.
//     Squash never touched: v1 reads 21MB in 64B segments (50% sectors,
//     scalar 4B/lane loads) -> ~14.5us for a 3.3us-at-BW job.
// R19 squash v2: float4 granularity, identical add order (bit-identical
// output). Thread (q,g4): sum 32 tiles of s_part float4 g4; per-wave loads
// are 4x 256B contiguous clusters (100% sectors); cross-q shfl_xor(1,2);
// ||s||^2 across the (b,o)'s 4 float4s via shfl_xor(4,8); q==0 lanes write
// float4 out/vsum coalesced. Grid 640x64, unroll 8 (8 loads in flight).

#define B    256
#define N    1152
#define NO   10
#define DI   8
#define DE   16
#define NTILE   9
#define NTILES  128    // N / NTILE
#define BPT     2      // b per thread
#define BG      128    // b per block
#define BGS     2      // B / BG
#define THREADS 640    // 10 waves, o = wave id
#define GRID    (NTILES * BGS)   // 256 blocks = 1/CU

// ws layout (floats)
#define SP_OFF 0
#define SP_SZ  (NTILES * B * NO * DE)   // 5,242,880
#define VS_OFF (SP_OFF + SP_SZ)
#define VS_SZ  (B * NO * DE)            // 40,960
#define UT_OFF (VS_OFF + VS_SZ)
#define UT_SZ  (2 * N * B * 4)          // 2,359,296 (= B*N*DI)

// ---------------------------------------------------------------------------
// One-time transpose: u (B,N,8) -> ut[((n*2+h)*B + b)*4 + j] = u[b][n][h*4+j]
// ---------------------------------------------------------------------------
__global__ __launch_bounds__(256)
void transpose_kernel(const float* __restrict__ u, float* __restrict__ ut) {
    const int lane = threadIdx.x & 63;
    const int wv   = threadIdx.x >> 6;           // 0..3 -> n offset
    const int n    = blockIdx.x * 4 + wv;
    const int b    = blockIdx.y * 64 + lane;
    const float* up = u + ((size_t)b * N + n) * DI;
    const float4 a0 = *(const float4*)up;
    const float4 a1 = *(const float4*)(up + 4);
    *(float4*)(ut + ((size_t)(n * 2 + 0) * B + b) * 4) = a0;
    *(float4*)(ut + ((size_t)(n * 2 + 1) * B + b) * 4) = a1;
}

// ---------------------------------------------------------------------------
// Routing pass (R18, unchanged). Grid: 256 blocks x 640 threads. 1 block/CU.
// Block id encodes (tile t, b-group g) with same-tile blocks on one XCD:
//   id = (t&7) + 8*((t>>3) + 16*g)
// ---------------------------------------------------------------------------
__global__ __launch_bounds__(THREADS, 3)
void routing_kernel(const float* __restrict__ u,
                    const float* __restrict__ ut,
                    const float* __restrict__ w,
                    const float* __restrict__ bias,
                    const float* __restrict__ vsum,
                    float* __restrict__ s_part,
                    const int has_v,
                    const int use_ut) {
    __shared__ float wt[NTILE * NO * DI * DE];  // 46,080 B weight tile
    __shared__ float lgx[2][NO][BG];            // 10 KB double-buffered exchange
    const int tid  = threadIdx.x;
    const int lane = tid & 63;
    const int wv   = __builtin_amdgcn_readfirstlane(tid >> 6);  // 0..9, uniform
    const int o    = wv;                         // one output capsule per wave

    const int id   = blockIdx.x;
    const int xcd  = id & 7;
    const int sg   = id >> 3;                    // 0..31
    const int g    = sg >> 4;                    // 0..1  (b-group)
    const int t    = ((sg & 15) << 3) | xcd;     // 0..127 (tile)
    const int n0   = t * NTILE;
    const int bb   = g * BG;                     // block's b base

    // Stage the tile's weights: 11520 floats = 2880 float4, coalesced.
    {
        const float4* wg = (const float4*)(w + (size_t)n0 * NO * DI * DE);
        float4* wl = (float4*)wt;
#pragma unroll
        for (int c = 0; c < 5; ++c) {
            const int idx = c * THREADS + tid;
            if (idx < (NTILE * NO * DI * DE) / 4)
                wl[idx] = wg[idx];
        }
    }

    // Bias for this wave's o, all 9 n of the tile (scalar path, tiny).
    float bvs[NTILE];
#pragma unroll
    for (int i = 0; i < NTILE; ++i)
        bvs[i] = bias[(n0 + i) * NO + o];

    // vsum fragments for this thread's 2 b values — loop-invariant
    float4 vv[BPT][4];
#pragma unroll
    for (int bi = 0; bi < BPT; ++bi)
#pragma unroll
        for (int eq = 0; eq < 4; ++eq)
            vv[bi][eq] = make_float4(0.f, 0.f, 0.f, 0.f);
    if (has_v) {
#pragma unroll
        for (int bi = 0; bi < BPT; ++bi)
#pragma unroll
            for (int eq = 0; eq < 4; ++eq)
                vv[bi][eq] = *(const float4*)(vsum +
                    ((size_t)(bb + bi * 64 + lane) * NO + o) * DE + eq * 4);
    }

    float4 acc[BPT][4];
#pragma unroll
    for (int bi = 0; bi < BPT; ++bi)
#pragma unroll
        for (int eq = 0; eq < 4; ++eq)
            acc[bi][eq] = make_float4(0.f, 0.f, 0.f, 0.f);

    __syncthreads();   // weights staged

    for (int i = 0; i < NTILE; ++i) {
        const int n = n0 + i;

        // u rows for this thread's 2 b — coalesced from ut, or legacy gather
        float ur[BPT][DI];
#pragma unroll
        for (int bi = 0; bi < BPT; ++bi) {
            const int b = bb + bi * 64 + lane;
            float4 u0, u1;
            if (use_ut) {
                const float* up = ut + ((size_t)(n * 2) * B + b) * 4;
                u0 = *(const float4*)up;
                u1 = *(const float4*)(up + B * 4);
            } else {
                const float* up = u + ((size_t)b * N + n) * DI;
                u0 = *(const float4*)up;
                u1 = *(const float4*)(up + 4);
            }
            ur[bi][0] = u0.x; ur[bi][1] = u0.y; ur[bi][2] = u0.z; ur[bi][3] = u0.w;
            ur[bi][4] = u1.x; ur[bi][5] = u1.y; ur[bi][6] = u1.z; ur[bi][7] = u1.w;
        }

        // u_ji for this wave's o, both b — weights from LDS (uniform-address
        // ds_read_b128 broadcasts, conflict-free).
        const float* wrow = wt + (i * NO + o) * (DI * DE);
        const float bv = bvs[i];
        float4 uji[BPT][4];
#pragma unroll
        for (int bi = 0; bi < BPT; ++bi)
#pragma unroll
            for (int eq = 0; eq < 4; ++eq)
                uji[bi][eq] = make_float4(bv, bv, bv, bv);
#pragma unroll
        for (int d = 0; d < DI; ++d) {
#pragma unroll
            for (int eq = 0; eq < 4; ++eq) {
                const float4 w4 = *(const float4*)(wrow + d * DE + eq * 4);
#pragma unroll
                for (int bi = 0; bi < BPT; ++bi) {
                    uji[bi][eq].x += ur[bi][d] * w4.x;
                    uji[bi][eq].y += ur[bi][d] * w4.y;
                    uji[bi][eq].z += ur[bi][d] * w4.z;
                    uji[bi][eq].w += ur[bi][d] * w4.w;
                }
            }
        }

        float c[BPT];
        if (has_v) {
            const int pb = i & 1;
            // logits: full-e dot in-thread, exchange via LDS for the softmax
#pragma unroll
            for (int bi = 0; bi < BPT; ++bi) {
                float lg = 0.f;
#pragma unroll
                for (int eq = 0; eq < 4; ++eq)
                    lg += uji[bi][eq].x * vv[bi][eq].x + uji[bi][eq].y * vv[bi][eq].y
                        + uji[bi][eq].z * vv[bi][eq].z + uji[bi][eq].w * vv[bi][eq].w;
                lgx[pb][o][bi * 64 + lane] = lg;
            }
            __syncthreads();
#pragma unroll
            for (int bi = 0; bi < BPT; ++bi) {
                float l[NO];
#pragma unroll
                for (int oo = 0; oo < NO; ++oo) l[oo] = lgx[pb][oo][bi * 64 + lane];
                float m = l[0];
#pragma unroll
                for (int oo = 1; oo < NO; ++oo) m = fmaxf(m, l[oo]);
                float sum = 0.f;
#pragma unroll
                for (int oo = 0; oo < NO; ++oo) { l[oo] = __expf(l[oo] - m); sum += l[oo]; }
                c[bi] = l[o] / sum;
            }
            // no second barrier: buffer pb next written at i+2, separated by
            // the barrier at i+1.
        } else {
            c[0] = 0.1f; c[1] = 0.1f;   // softmax of zeros
        }

#pragma unroll
        for (int bi = 0; bi < BPT; ++bi)
#pragma unroll
            for (int eq = 0; eq < 4; ++eq) {
                acc[bi][eq].x += c[bi] * uji[bi][eq].x;
                acc[bi][eq].y += c[bi] * uji[bi][eq].y;
                acc[bi][eq].z += c[bi] * uji[bi][eq].z;
                acc[bi][eq].w += c[bi] * uji[bi][eq].w;
            }
    }

    // s_part[tile][b][o][e] — same layout squash expects
#pragma unroll
    for (int bi = 0; bi < BPT; ++bi) {
        float* sp = s_part + (((size_t)t * B + bb + bi * 64 + lane) * NO + o) * DE;
#pragma unroll
        for (int eq = 0; eq < 4; ++eq)
            *(float4*)(sp + eq * 4) = acc[bi][eq];
    }
}

// ---------------------------------------------------------------------------
// Squash v2: float4-coalesced. idx = (g4, q): thread sums 32 tiles of
// float4 #g4; cross-q shfl_xor(1,2) [same add order as v1 -> bit-identical];
// ||s||^2 over the (b,o)'s 4 float4s via shfl_xor(4,8); q==0 writes float4.
// Grid 640 x 64 (exactly 4*B*NO*DE/4 items).
// ---------------------------------------------------------------------------
__global__ __launch_bounds__(64)
void squash_kernel(const float* __restrict__ s_part,
                   float* __restrict__ vsum,
                   float* __restrict__ out,
                   const int accum) {
    const int idx = blockIdx.x * 64 + threadIdx.x;   // < 40960
    const int q   = idx & 3;                         // tile quarter
    const int g4  = idx >> 2;                        // float4 index, < 10240

    float4 s4 = make_float4(0.f, 0.f, 0.f, 0.f);
    const float4* sp = (const float4*)s_part
                     + (size_t)(q * 32) * (B * NO * DE / 4) + g4;
#pragma unroll 8
    for (int i = 0; i < 32; ++i) {
        const float4 v = sp[(size_t)i * (B * NO * DE / 4)];
        s4.x += v.x; s4.y += v.y; s4.z += v.z; s4.w += v.w;
    }
    // cross-q reduce (xor 1 then 2 — same tree as v1)
    s4.x += __shfl_xor(s4.x, 1); s4.y += __shfl_xor(s4.y, 1);
    s4.z += __shfl_xor(s4.z, 1); s4.w += __shfl_xor(s4.w, 1);
    s4.x += __shfl_xor(s4.x, 2); s4.y += __shfl_xor(s4.y, 2);
    s4.z += __shfl_xor(s4.z, 2); s4.w += __shfl_xor(s4.w, 2);

    // ||s||^2 for this (b,o): 4 float4s live on lanes differing in bits 2-3
    float nsq = s4.x * s4.x + s4.y * s4.y + s4.z * s4.z + s4.w * s4.w;
    nsq += __shfl_xor(nsq, 4);
    nsq += __shfl_xor(nsq, 8);

    const float nrm   = sqrtf(nsq);
    const float scale = nrm / (1.f + nsq);
    const float4 val  = make_float4(s4.x * scale, s4.y * scale,
                                    s4.z * scale, s4.w * scale);

    if (q == 0) {
        ((float4*)out)[g4] = val;                    // (B,NO,DE)
        if (accum) {
            const float4 vo = ((const float4*)vsum)[g4];
            ((float4*)vsum)[g4] = make_float4(vo.x + val.x, vo.y + val.y,
                                              vo.z + val.z, vo.w + val.w);
        } else {
            ((float4*)vsum)[g4] = val;
        }
    }
}

extern "C" void kernel_launch(void* const* d_in, const int* in_sizes, int n_in,
                              void* d_out, int out_size, void* d_ws, size_t ws_size,
                              hipStream_t stream) {
    const float* u    = (const float*)d_in[0];
    const float* w    = (const float*)d_in[1];   // (N,NO,DI,DE)
    const float* bias = (const float*)d_in[2];   // (N,NO)
    // d_in[3] = r, static 3

    float* wsf    = (float*)d_ws;
    float* s_part = wsf + SP_OFF;
    float* vsum   = wsf + VS_OFF;
    float* ut     = wsf + UT_OFF;
    float* out    = (float*)d_out;

    const int use_ut = (ws_size >= (size_t)(SP_SZ + VS_SZ + UT_SZ) * sizeof(float));

    if (use_ut)
        transpose_kernel<<<dim3(N / 4, B / 64), 256, 0, stream>>>(u, ut);

    for (int it = 0; it < 3; ++it) {
        routing_kernel<<<GRID, THREADS, 0, stream>>>(
            u, ut, w, bias, vsum, s_part, it > 0, use_ut);
        squash_kernel<<<(B * NO * DE) / 64, 64, 0, stream>>>(
            s_part, vsum, out, it > 0);
    }
}